// Round 3
// baseline (1291.414 us; speedup 1.0000x reference)
//
#include <hip/hip_runtime.h>

#define TOK   8192
#define HD    1024
#define NI    2816
#define NI2   5632
#define NEXP  8
#define MAXROWS 16896

typedef __attribute__((ext_vector_type(8))) short short8;
typedef __attribute__((ext_vector_type(4))) short short4v;
typedef __attribute__((ext_vector_type(4))) float f32x4;

// ---------- helpers ----------
__device__ __forceinline__ float bf2f(short v) {
    union { unsigned u; float f; } c; c.u = ((unsigned)(unsigned short)v) << 16; return c.f;
}
__device__ __forceinline__ short f2bf(float f) {
    union { float f; unsigned u; } c; c.f = f;
    unsigned r = c.u + 0x7fff + ((c.u >> 16) & 1);   // RNE
    return (short)(r >> 16);
}
// swizzled LDS: (row,kgroup-of-8) at row*40 + ((kg ^ ((row>>3)&3))*8)
__device__ __forceinline__ int ldsvec(int row, int kg) {
    return row * 40 + ((kg ^ ((row >> 3) & 3)) << 3);
}

// ---------- 0. dtype detect: fp32 read as bf16 has huge exponents ----------
__global__ void detect_kernel(const unsigned short* __restrict__ xs, int* __restrict__ ctrl)
{
    int bad = 0;
    for (int i = threadIdx.x; i < 4096; i += 256) {
        int e = (xs[i] >> 7) & 0xFF;          // bf16 exponent field
        if (e >= 137) bad = 1;                // |v| >= 1024 (or Inf/NaN)
    }
    if (bad) atomicOr(&ctrl[31], 1);          // flag=1 -> inputs are fp32
}

// ---------- 0b. x -> bf16 (convert or copy) ----------
__global__ __launch_bounds__(256) void cvt_x_kernel(
    const void* __restrict__ xraw, short* __restrict__ xbf, const int* __restrict__ ctrl)
{
    int i = blockIdx.x * 256 + threadIdx.x;
    int flag = ctrl[31];
    xbf[i] = flag ? f2bf(((const float*)xraw)[i]) : ((const short*)xraw)[i];
}

// ---------- 0c. weight fp32 -> bf16 (no-op unless flag) ----------
__global__ __launch_bounds__(256) void cvt_w_kernel(
    const float* __restrict__ src, short* __restrict__ dst, const int* __restrict__ ctrl)
{
    if (!ctrl[31]) return;
    int i = blockIdx.x * 256 + threadIdx.x;
    f32x4 v = ((const f32x4*)src)[i];
    short4v o;
    o.x = f2bf(v.x); o.y = f2bf(v.y); o.z = f2bf(v.z); o.w = f2bf(v.w);
    ((short4v*)dst)[i] = o;
}

// ---------- 1. gating: logits -> top2 -> renorm ----------
__global__ __launch_bounds__(256) void gate_kernel(
    const void* __restrict__ xraw, const void* __restrict__ gwraw,
    int* __restrict__ top_i, float* __restrict__ top_w, int* __restrict__ ctrl)
{
    const int flag = ctrl[31];
    const float* xf = (const float*)xraw;  const short* xs = (const short*)xraw;
    const float* gf = (const float*)gwraw; const short* gs = (const short*)gwraw;
    const int wave = threadIdx.x >> 6, lane = threadIdx.x & 63;
    const int t = blockIdx.x * 4 + wave;
    float acc[NEXP] = {0.f, 0.f, 0.f, 0.f, 0.f, 0.f, 0.f, 0.f};
    for (int i = lane; i < HD; i += 64) {
        float xv = flag ? xf[t * HD + i] : bf2f(xs[t * HD + i]);
#pragma unroll
        for (int e = 0; e < NEXP; e++) {
            float wv = flag ? gf[e * HD + i] : bf2f(gs[e * HD + i]);
            acc[e] += xv * wv;
        }
    }
#pragma unroll
    for (int e = 0; e < NEXP; e++)
        for (int off = 32; off > 0; off >>= 1) acc[e] += __shfl_down(acc[e], off, 64);
    if (lane == 0) {
        int a = 0; float va = acc[0];
#pragma unroll
        for (int e = 1; e < NEXP; e++) if (acc[e] > va) { a = e; va = acc[e]; }
        int b = -1; float vb = -1e30f;
#pragma unroll
        for (int e = 0; e < NEXP; e++) if (e != a && acc[e] > vb) { b = e; vb = acc[e]; }
        float r = __expf(vb - va);
        float wa = 1.f / (1.f + r), wb = r / (1.f + r);
        top_i[2 * t] = a;     top_w[2 * t] = wa;
        top_i[2 * t + 1] = b; top_w[2 * t + 1] = wb;
        atomicAdd(&ctrl[a], 1);
        atomicAdd(&ctrl[b], 1);
    }
}

// ---------- 2. offsets (padded to 64) + pad dummy rows ----------
__global__ void offsets_pad_kernel(int* __restrict__ ctrl,
                                   int* __restrict__ rows_tok, float* __restrict__ rows_w)
{
    __shared__ int soff[NEXP + 1];
    if (threadIdx.x == 0) {
        int off = 0;
        for (int e = 0; e < NEXP; e++) {
            soff[e] = off; ctrl[16 + e] = off;
            off += (ctrl[e] + 63) & ~63;
        }
        soff[NEXP] = off; ctrl[24] = off;
    }
    __syncthreads();
    for (int e = 0; e < NEXP; e++) {
        int c = ctrl[e];
        int start = soff[e], len = soff[e + 1] - soff[e];
        for (int s = c + (int)threadIdx.x; s < len; s += blockDim.x) {
            rows_tok[start + s] = 0;
            rows_w[start + s] = 0.f;
        }
    }
}

// ---------- 3. scatter tokens into expert row lists ----------
__global__ __launch_bounds__(256) void scatter_kernel(
    const int* __restrict__ top_i, const float* __restrict__ top_w,
    int* __restrict__ ctrl, int* __restrict__ rows_tok, float* __restrict__ rows_w)
{
    int t = blockIdx.x * 256 + threadIdx.x;
    if (t >= TOK) return;
#pragma unroll
    for (int k = 0; k < 2; k++) {
        int e = top_i[2 * t + k];
        int pos = atomicAdd(&ctrl[8 + e], 1);
        int row = ctrl[16 + e] + pos;
        rows_tok[row] = t;
        rows_w[row] = top_w[2 * t + k];
    }
}

// ---------- 4. GEMM1: act = silu(x@Wg) * (x@Wu) ----------
__global__ __launch_bounds__(256) void gemm1_kernel(
    const short* __restrict__ xbf, const void* __restrict__ w1raw,
    const short* __restrict__ w1bf,
    const int* __restrict__ rows_tok, const int* __restrict__ ctrl,
    short* __restrict__ act_g, int i0base, int chunk_cols, int conv)
{
    const int row0 = blockIdx.y * 64;
    if (row0 >= ctrl[24]) return;
    const int flag = ctrl[31];
    const int use_bf = (!flag) || conv;
    int e = 0;
#pragma unroll
    for (int q = 1; q < NEXP; q++) if (row0 >= ctrl[16 + q]) e = q;
    const int i0off = blockIdx.x * 64;
    const int i0 = i0base + i0off;

    __shared__ __align__(16) short As[2560];
    __shared__ __align__(16) short Bg[2560];
    __shared__ __align__(16) short Bu[2560];
    __shared__ int toks[64];

    const int tid = threadIdx.x;
    if (tid < 64) toks[tid] = rows_tok[row0 + tid];
    __syncthreads();

    const int am = tid >> 2, acg = tid & 3;
    const short* aptr = xbf + toks[am] * HD + acg * 8;

    const int half = tid >> 7;                 // 0=gate cols, 1=up cols
    const int i2 = tid & 127;
    const int bq = i2 >> 3;                    // k-pair 2bq,2bq+1
    const int bng = i2 & 7;                    // n-group of 8 cols
    const int bofs = e * (HD * NI2) + i0 + half * NI + bng * 8;
    const short* bb16 = (flag ? w1bf : (const short*)w1raw) + bofs;
    const float* bf32 = (const float*)w1raw + bofs;
    short* Bs = half ? Bu : Bg;
    const int bkg = bq >> 2, bkin = (2 * bq) & 7;
    const int boff = bng * 320 + ((bkg ^ (bng & 3)) << 3) + bkin;

    const int lane = tid & 63, wave = tid >> 6;
    const int lm = lane & 15, lq = lane >> 4;

    const f32x4 zero = {0.f, 0.f, 0.f, 0.f};
    f32x4 accg[4], accu[4];
#pragma unroll
    for (int i = 0; i < 4; i++) { accg[i] = zero; accu[i] = zero; }

    for (int kk = 0; kk < HD; kk += 32) {
        short8 av = *(const short8*)(aptr + kk);
        unsigned pv[8];
        if (use_bf) {
            const short* bp = bb16 + (kk + 2 * bq) * NI2;
            short8 b0 = *(const short8*)(bp);
            short8 b1 = *(const short8*)(bp + NI2);
#pragma unroll
            for (int j = 0; j < 8; j++)
                pv[j] = ((unsigned)(unsigned short)b0[j]) |
                        (((unsigned)(unsigned short)b1[j]) << 16);
        } else {
            const float* bp = bf32 + (kk + 2 * bq) * NI2;
            f32x4 c0 = *(const f32x4*)(bp);
            f32x4 c1 = *(const f32x4*)(bp + 4);
            f32x4 d0 = *(const f32x4*)(bp + NI2);
            f32x4 d1 = *(const f32x4*)(bp + NI2 + 4);
            float b0f[8] = {c0.x, c0.y, c0.z, c0.w, c1.x, c1.y, c1.z, c1.w};
            float b1f[8] = {d0.x, d0.y, d0.z, d0.w, d1.x, d1.y, d1.z, d1.w};
#pragma unroll
            for (int j = 0; j < 8; j++)
                pv[j] = ((unsigned)(unsigned short)f2bf(b0f[j])) |
                        (((unsigned)(unsigned short)f2bf(b1f[j])) << 16);
        }
        *(short8*)(&As[ldsvec(am, acg)]) = av;
#pragma unroll
        for (int j = 0; j < 8; j++)
            *(unsigned*)(&Bs[boff + j * 40]) = pv[j];
        __syncthreads();
        short8 af = *(const short8*)(&As[ldsvec(wave * 16 + lm, lq)]);
#pragma unroll
        for (int ns = 0; ns < 4; ns++) {
            short8 bg = *(const short8*)(&Bg[ldsvec(ns * 16 + lm, lq)]);
            short8 bu = *(const short8*)(&Bu[ldsvec(ns * 16 + lm, lq)]);
            accg[ns] = __builtin_amdgcn_mfma_f32_16x16x32_bf16(af, bg, accg[ns], 0, 0, 0);
            accu[ns] = __builtin_amdgcn_mfma_f32_16x16x32_bf16(af, bu, accu[ns], 0, 0, 0);
        }
        __syncthreads();
    }
#pragma unroll
    for (int ns = 0; ns < 4; ns++) {
#pragma unroll
        for (int r = 0; r < 4; r++) {
            int row = row0 + wave * 16 + lq * 4 + r;   // C/D: row=(lane>>4)*4+r
            int col = i0off + ns * 16 + lm;            // chunk-local column
            float g = accg[ns][r], u = accu[ns][r];
            float a = (g / (1.f + __expf(-g))) * u;
            act_g[(long)row * chunk_cols + col] = f2bf(a);
        }
    }
}

// ---------- 5. GEMM2: partial act@W2, scaled-atomic into fp32 dst ----------
__global__ __launch_bounds__(256) void gemm2_kernel(
    const short* __restrict__ act_g, const void* __restrict__ w2raw,
    const short* __restrict__ w2bf,
    const int* __restrict__ rows_tok, const float* __restrict__ rows_w,
    const int* __restrict__ ctrl, float* __restrict__ accum, float* __restrict__ doutf,
    int i0base, int chunk_cols, int conv)
{
    const int row0 = blockIdx.y * 64;
    if (row0 >= ctrl[24]) return;
    const int flag = ctrl[31];
    const int use_bf = (!flag) || conv;
    int e = 0;
#pragma unroll
    for (int q = 1; q < NEXP; q++) if (row0 >= ctrl[16 + q]) e = q;
    const int n0 = blockIdx.x * 64;

    __shared__ __align__(16) short As[2560];
    __shared__ __align__(16) short Bs[2560];
    __shared__ int toks[64];
    __shared__ float rws[64];

    const int tid = threadIdx.x;
    if (tid < 64) { toks[tid] = rows_tok[row0 + tid]; rws[tid] = rows_w[row0 + tid]; }
    __syncthreads();

    const int am = tid >> 2, acg = tid & 3;
    const short* aptr = act_g + (long)(row0 + am) * chunk_cols + acg * 8;

    const int i2 = tid & 127;
    const int bq = i2 >> 3, bng = i2 & 7;
    const int bofs = e * (NI * HD) + n0 + bng * 8;
    const short* bb16 = (flag ? w2bf : (const short*)w2raw) + bofs;
    const float* bf32 = (const float*)w2raw + bofs;
    const int bkg = bq >> 2, bkin = (2 * bq) & 7;
    const int boff = bng * 320 + ((bkg ^ (bng & 3)) << 3) + bkin;

    const int lane = tid & 63, wave = tid >> 6;
    const int lm = lane & 15, lq = lane >> 4;

    const f32x4 zero = {0.f, 0.f, 0.f, 0.f};
    f32x4 acc[4];
#pragma unroll
    for (int i = 0; i < 4; i++) acc[i] = zero;

    for (int kk = 0; kk < chunk_cols; kk += 32) {
        short8 av = *(const short8*)(aptr + kk);
        unsigned pv[8];
        if (tid < 128) {
            if (use_bf) {
                const short* bp = bb16 + (long)(i0base + kk + 2 * bq) * HD;
                short8 b0 = *(const short8*)(bp);
                short8 b1 = *(const short8*)(bp + HD);
#pragma unroll
                for (int j = 0; j < 8; j++)
                    pv[j] = ((unsigned)(unsigned short)b0[j]) |
                            (((unsigned)(unsigned short)b1[j]) << 16);
            } else {
                const float* bp = bf32 + (long)(i0base + kk + 2 * bq) * HD;
                f32x4 c0 = *(const f32x4*)(bp);
                f32x4 c1 = *(const f32x4*)(bp + 4);
                f32x4 d0 = *(const f32x4*)(bp + HD);
                f32x4 d1 = *(const f32x4*)(bp + HD + 4);
                float b0f[8] = {c0.x, c0.y, c0.z, c0.w, c1.x, c1.y, c1.z, c1.w};
                float b1f[8] = {d0.x, d0.y, d0.z, d0.w, d1.x, d1.y, d1.z, d1.w};
#pragma unroll
                for (int j = 0; j < 8; j++)
                    pv[j] = ((unsigned)(unsigned short)f2bf(b0f[j])) |
                            (((unsigned)(unsigned short)f2bf(b1f[j])) << 16);
            }
        }
        *(short8*)(&As[ldsvec(am, acg)]) = av;
        if (tid < 128) {
#pragma unroll
            for (int j = 0; j < 8; j++)
                *(unsigned*)(&Bs[boff + j * 40]) = pv[j];
        }
        __syncthreads();
        short8 af = *(const short8*)(&As[ldsvec(wave * 16 + lm, lq)]);
#pragma unroll
        for (int ns = 0; ns < 4; ns++) {
            short8 bf = *(const short8*)(&Bs[ldsvec(ns * 16 + lm, lq)]);
            acc[ns] = __builtin_amdgcn_mfma_f32_16x16x32_bf16(af, bf, acc[ns], 0, 0, 0);
        }
        __syncthreads();
    }
    float* dst = flag ? doutf : accum;
#pragma unroll
    for (int ns = 0; ns < 4; ns++) {
#pragma unroll
        for (int r = 0; r < 4; r++) {
            int rl = wave * 16 + lq * 4 + r;
            float w = rws[rl];
            if (w != 0.f) {
                int tok = toks[rl];
                atomicAdd(&dst[tok * HD + n0 + ns * 16 + lm], acc[ns][r] * w);
            }
        }
    }
}

// ---------- 6. fp32 accum -> bf16 out (bf16 mode only) ----------
__global__ __launch_bounds__(256) void convert_kernel(
    const float* __restrict__ accum, short* __restrict__ out, const int* __restrict__ ctrl)
{
    if (ctrl[31]) return;   // fp32 mode: gemm2 wrote d_out directly
    int i = blockIdx.x * 256 + threadIdx.x;
    out[i] = f2bf(accum[i]);
}

extern "C" void kernel_launch(void* const* d_in, const int* in_sizes, int n_in,
                              void* d_out, int out_size, void* d_ws, size_t ws_size,
                              hipStream_t stream) {
    char* ws = (char*)d_ws;
    // layout: ctrl[0,512) | top_i | top_w | rows_tok | rows_w | x_bf | act chunk | shared
    int*   ctrl     = (int*)ws;
    int*   top_i    = (int*)(ws + 512);
    float* top_w    = (float*)(ws + 66048);
    int*   rows_tok = (int*)(ws + 131584);
    float* rows_w   = (float*)(ws + 199168);
    short* xbf      = (short*)(ws + 266752);
    short* act_g    = (short*)(ws + 17043968);

    const long fixed = 17043968;
    const long per_cb = (long)MAXROWS * 64 * 2;        // 2,162,688
    const long wbytes = 138412032;                     // w1_bf + w2_bf
    int conv = 0; long CB;
    if ((long)ws_size >= fixed + per_cb + wbytes) {
        conv = 1;
        CB = ((long)ws_size - fixed - wbytes) / per_cb;
    } else {
        CB = ((long)ws_size - fixed - 33554432) / per_cb;
    }
    if (CB > 44) CB = 44;
    if (CB < 1)  CB = 1;
    const long shared_off = fixed + CB * per_cb;
    float* accum = (float*)(ws + shared_off);          // flag==0 use
    short* w1bf  = (short*)(ws + shared_off);          // flag==1 && conv use (exclusive)
    short* w2bf  = (short*)(ws + shared_off + 92274688);

    hipMemsetAsync(ws, 0, 512, stream);                                // ctrl
    long zlen = 33554432;
    if (shared_off + zlen > (long)ws_size) zlen = (long)ws_size - shared_off;
    if (zlen > 0) hipMemsetAsync(ws + shared_off, 0, (size_t)zlen, stream);  // accum
    hipMemsetAsync(d_out, 0, (size_t)out_size * 2, stream);            // safe for both dtypes

    detect_kernel<<<1, 256, 0, stream>>>((const unsigned short*)d_in[0], ctrl);
    cvt_x_kernel<<<TOK * HD / 256, 256, 0, stream>>>(d_in[0], xbf, ctrl);
    if (conv) {
        cvt_w_kernel<<<NEXP * HD * NI2 / 4 / 256, 256, 0, stream>>>((const float*)d_in[2], w1bf, ctrl);
        cvt_w_kernel<<<NEXP * NI * HD / 4 / 256, 256, 0, stream>>>((const float*)d_in[3], w2bf, ctrl);
    }
    gate_kernel<<<TOK / 4, 256, 0, stream>>>(d_in[0], d_in[1], top_i, top_w, ctrl);
    offsets_pad_kernel<<<1, 256, 0, stream>>>(ctrl, rows_tok, rows_w);
    scatter_kernel<<<TOK / 256, 256, 0, stream>>>(top_i, top_w, ctrl, rows_tok, rows_w);

    for (int i0base = 0; i0base < NI; i0base += (int)CB * 64) {
        int cols = NI - i0base; if (cols > (int)CB * 64) cols = (int)CB * 64;
        gemm1_kernel<<<dim3(cols / 64, MAXROWS / 64), 256, 0, stream>>>(
            xbf, d_in[2], w1bf, rows_tok, ctrl, act_g, i0base, cols, conv);
        gemm2_kernel<<<dim3(HD / 64, MAXROWS / 64), 256, 0, stream>>>(
            act_g, d_in[3], w2bf, rows_tok, rows_w, ctrl, accum, (float*)d_out,
            i0base, cols, conv);
    }
    convert_kernel<<<TOK * HD / 256, 256, 0, stream>>>(accum, (short*)d_out, ctrl);
}